// Round 9
// baseline (3294.286 us; speedup 1.0000x reference)
//
#include <hip/hip_runtime.h>
#include <hip/hip_bf16.h>
#include <math.h>

// Problem constants
#define BB 16
#define SS 1024
#define EE 256
#define HH 256
#define G4 1024      // 4*H

// LSTM decomposition: 32 clusters = (2 dir) x (16 samples). Each cluster =
// 8 WGs, one per 32-hidden-col block. FLAG-FREE sync via self-tagged 8-byte
// words (h bits | epoch<<32), relaxed agent-scope atomics, s_sleep backoff.
// Wave-local cell ownership: each wave owns 4 cells; k-reduce + gate gather
// + state update all intra-wave (shfl) -> ONE barrier per step.
#define NCB 8        // col blocks
#define CBC 32       // cols per block
#define LTHR 512     // threads per lstm WG
#define NCLUST 32    // clusters
#define CLW 256      // tagged h words per cluster (1 sample * 256 cols)

// Workspace layout (bytes)
static constexpr size_t HBUF_OFF = 0;                          // u64[2 par][32 cluster][256] = 128 KB
static constexpr size_t HBUF_BYTES = (size_t)2 * NCLUST * CLW * 8;     // 131072
static constexpr size_t LEN_OFF  = 131072;                     // 16 int
static constexpr size_t HIST_OFF = 139264;                     // [2 dir][16 b][1024 t][256 j] f32 = 32 MB
static constexpr size_t XPF_OFF  = HIST_OFF + (size_t)2*BB*SS*HH*4;    // +64 MB
static constexpr size_t XPB_OFF  = XPF_OFF + (size_t)BB*SS*G4*4;       // +64 MB

// ---------------- K1: lengths from mask (format auto-detect) ----------------
__global__ void len_kernel(const void* __restrict__ mask, int* __restrict__ lengths)
{
    const int b = blockIdx.x;
    const int t = threadIdx.x;
    const unsigned char* mb = (const unsigned char*)mask;
    const bool byteFmt = (mb[1] != 0);   // lengths >= 512 so element 1 is always true
    int cnt = 0;
    if (byteFmt) {
        const unsigned char* row = mb + (size_t)b * SS;
        for (int i = t; i < SS; i += 256) cnt += (row[i] != 0);
    } else {
        const int* row = ((const int*)mask) + (size_t)b * SS;
        for (int i = t; i < SS; i += 256) cnt += (row[i] != 0);
    }
    __shared__ int sred[256];
    sred[t] = cnt;
    __syncthreads();
    for (int s = 128; s > 0; s >>= 1) { if (t < s) sred[t] += sred[t + s]; __syncthreads(); }
    if (t == 0) lengths[b] = sred[0];
}

// ---------------- K2: fused embed-gather + input-projection GEMM ----------------
#define GB_BM 128
#define GB_BN 128
#define GB_BK 32
__global__ __launch_bounds__(256) void xp_gemm(
    const int* __restrict__ x, const float* __restrict__ emb,
    const float* __restrict__ wf, const float* __restrict__ bf,
    const float* __restrict__ wb, const float* __restrict__ bb,
    float* __restrict__ xpF, float* __restrict__ xpB)
{
    __shared__ float As[GB_BK][GB_BM + 4];
    __shared__ float Bs[GB_BK][GB_BN + 4];
    __shared__ int idxs[GB_BM];

    const int t = threadIdx.x;
    const int tokBase = blockIdx.x * GB_BM;
    const int nBase   = blockIdx.y * GB_BN;
    const int nOff    = nBase & (G4 - 1);
    const float* Wp   = (nBase < G4) ? wf : wb;

    if (t < GB_BM) idxs[t] = x[tokBase + t];
    __syncthreads();

    const int tx = t & 15, ty = t >> 4;
    float acc[8][8];
#pragma unroll
    for (int i = 0; i < 8; i++)
#pragma unroll
        for (int j = 0; j < 8; j++) acc[i][j] = 0.f;

    for (int k0 = 0; k0 < EE; k0 += GB_BK) {
#pragma unroll
        for (int it = 0; it < 4; ++it) {
            const int flat = t + it * 256;
            const int m  = flat & 127;
            const int kq = flat >> 7;
            const int idx = idxs[m];
            const float4 av = *(const float4*)(emb + (size_t)idx * EE + k0 + kq * 4);
            As[kq * 4 + 0][m] = av.x; As[kq * 4 + 1][m] = av.y;
            As[kq * 4 + 2][m] = av.z; As[kq * 4 + 3][m] = av.w;
            const float4 bv = *(const float4*)(Wp + (size_t)(nOff + m) * EE + k0 + kq * 4);
            Bs[kq * 4 + 0][m] = bv.x; Bs[kq * 4 + 1][m] = bv.y;
            Bs[kq * 4 + 2][m] = bv.z; Bs[kq * 4 + 3][m] = bv.w;
        }
        __syncthreads();
#pragma unroll
        for (int k = 0; k < GB_BK; k++) {
            const float4 a0 = *(const float4*)&As[k][ty * 8];
            const float4 a1 = *(const float4*)&As[k][ty * 8 + 4];
            const float4 b0 = *(const float4*)&Bs[k][tx * 8];
            const float4 b1 = *(const float4*)&Bs[k][tx * 8 + 4];
            const float a_[8] = {a0.x, a0.y, a0.z, a0.w, a1.x, a1.y, a1.z, a1.w};
            const float b_[8] = {b0.x, b0.y, b0.z, b0.w, b1.x, b1.y, b1.z, b1.w};
#pragma unroll
            for (int i = 0; i < 8; i++)
#pragma unroll
                for (int j = 0; j < 8; j++) acc[i][j] = fmaf(a_[i], b_[j], acc[i][j]);
        }
        __syncthreads();
    }

    const float* biasP = (nBase < G4) ? bf : bb;
    float bj[8];
#pragma unroll
    for (int j = 0; j < 8; j++) bj[j] = biasP[nOff + tx * 8 + j];
    float* outP = (nBase < G4) ? xpF : xpB;
#pragma unroll
    for (int i = 0; i < 8; i++) {
        const int token = tokBase + ty * 8 + i;
        float* row = outP + (size_t)token * G4 + nOff + tx * 8;
        float4 v0, v1;
        v0.x = acc[i][0] + bj[0]; v0.y = acc[i][1] + bj[1];
        v0.z = acc[i][2] + bj[2]; v0.w = acc[i][3] + bj[3];
        v1.x = acc[i][4] + bj[4]; v1.y = acc[i][5] + bj[5];
        v1.z = acc[i][6] + bj[6]; v1.w = acc[i][7] + bj[7];
        *(float4*)row = v0;
        *(float4*)(row + 4) = v1;
    }
}

// ---------------- K3: clustered bi-LSTM, self-tagged sync, 1 barrier/step ----------------
// Grid = 256 blocks: cluster = bid&31 (dir = cluster&1, smp = cluster>>1), cb = bid>>5.
// Wave w owns cells [w*4, w*4+4) of this WG's 32-col block. Lane role:
//   ks = l>>4 (k-quarter), gate = (l>>2)&3, cq = l&3 -> grow = gate*256+cb*32+w*4+cq.
// Dot: 64 reg-FMA vs h (LDS bcast); k-reduce via shfl_xor(16,32); activation on
// all lanes; gate gather via 4 in-wave shfl; lanes 0..3 update c/h and publish.
// W_hh slice (64 VGPR/thread) is PINNED via opaque asm so the allocator cannot
// demote it to per-step cache reloads (round-7 counter showed VGPR=52 -> W was
// being re-fetched from L2 every step, ~128 KB/WG/step on the critical path).
__global__ __launch_bounds__(LTHR, 2) void lstm_kernel(
    const float* __restrict__ xpF, const float* __restrict__ xpB,
    const float* __restrict__ whhF, const float* __restrict__ whhB,
    const int* __restrict__ lengths,
    unsigned long long* __restrict__ hbuf,  // [2 par][32 cluster][256]
    float* __restrict__ hist)               // [2 dir][16 b][1024 t][256 j]
{
    const int bid     = blockIdx.x;
    const int cluster = bid & 31;
    const int cb      = bid >> 5;
    const int dir     = cluster & 1;
    const int smp     = cluster >> 1;      // 0..15
    const int t       = threadIdx.x;
    const int w       = t >> 6;            // wave 0..7
    const int l       = t & 63;

    const float* xp  = dir ? xpB : xpF;
    const float* whh = dir ? whhB : whhF;

    // lane role
    const int ks   = l >> 4;               // k-quarter 0..3
    const int gate = (l >> 2) & 3;         // 0..3 (i,f,g,o)
    const int cq   = l & 3;                // cell-in-wave 0..3
    const int jloc = w * 4 + cq;           // local col 0..31
    const int grow = gate * HH + cb * CBC + jloc;  // global gate row
    const bool ks0 = (ks == 0);

    __shared__ float h_stage[2][4][68];    // [buf][ks][64 cols], padded

    // W_hh slice -> registers: row grow, k in [ks*64, ks*64+64)
    float4 Wc[16];
    {
        const float4* wp = (const float4*)(whh + (size_t)grow * HH + ks * 64);
#pragma unroll
        for (int q = 0; q < 16; q++) Wc[q] = wp[q];
    }
    // pin W in VGPRs: opaque asm "writes" each component -> cannot be
    // rematerialized from memory by the scheduler/allocator
#pragma unroll
    for (int q = 0; q < 16; q++)
        asm volatile("" : "+v"(Wc[q].x), "+v"(Wc[q].y), "+v"(Wc[q].z), "+v"(Wc[q].w));

    const int len = lengths[smp];
    float c_reg = 0.f, h_reg = 0.f;

    const unsigned long long* hRd0 = hbuf + cluster * CLW;
    const unsigned long long* hRd1 = hbuf + (size_t)NCLUST * CLW + cluster * CLW;
    unsigned long long* hWr0 = hbuf + cluster * CLW;
    unsigned long long* hWr1 = hbuf + (size_t)NCLUST * CLW + cluster * CLW;

    for (int n = 0; n < SS; ++n) {
        const int ts    = dir ? (SS - 1 - n) : n;
        const int par_r = (n + 1) & 1;       // parity holding h_{n-1}
        const int par_w = n & 1;

        // prefetch xp for this gate row (only meaningful on ks0 lanes)
        float xpv = 0.f;
        if (ks0) xpv = xp[((size_t)smp * SS + ts) * G4 + grow];

        // --- stage h_{n-1}: poll self-tagged words (t<256), backoff on miss ---
        if (t < 256) {
            const unsigned long long* src = (par_r ? hRd1 : hRd0) + t;
            unsigned long long v = __hip_atomic_load(src, __ATOMIC_RELAXED,
                                                     __HIP_MEMORY_SCOPE_AGENT);
            while ((unsigned int)(v >> 32) < (unsigned int)n) {
                __builtin_amdgcn_s_sleep(1);
                v = __hip_atomic_load(src, __ATOMIC_RELAXED,
                                      __HIP_MEMORY_SCOPE_AGENT);
            }
            h_stage[par_r][t >> 6][t & 63] = __builtin_bit_cast(float, (unsigned int)v);
        }
        __syncthreads();   // B1: h staged (sole barrier; stage is LDS-double-buffered)

        // --- dot: W (regs) x h (LDS bcast, conflict-free across ks groups) ---
        float a = 0.f;
        {
            const float4* hp = (const float4*)&h_stage[par_r][ks][0];
#pragma unroll
            for (int q = 0; q < 16; q++) {
                const float4 w4 = Wc[q], h4 = hp[q];
                a = fmaf(w4.x, h4.x, a); a = fmaf(w4.y, h4.y, a);
                a = fmaf(w4.z, h4.z, a); a = fmaf(w4.w, h4.w, a);
            }
        }
        // k-reduce across the 4 ks groups (intra-wave)
        a += __shfl_xor(a, 16);
        a += __shfl_xor(a, 32);

        // activation (correct on ks0 lanes; garbage elsewhere, never consumed)
        const float gv  = a + xpv;
        const float act = (gate == 2) ? tanhf(gv) : 1.f / (1.f + expf(-gv));

        // gather the 4 gates of cell cq from ks0 lanes (gate*4 + cq)
        const float iv = __shfl(act, cq);
        const float fv = __shfl(act, 4 + cq);
        const float gg = __shfl(act, 8 + cq);
        const float ov = __shfl(act, 12 + cq);

        // --- state update (lanes 0..3 of each wave own cells w*4+l) + publish ---
        if (l < 4) {
            const float cn = fmaf(fv, c_reg, iv * gg);
            const float hn = ov * tanhf(cn);
            const bool m = (ts < len);
            if (m) { c_reg = cn; h_reg = hn; }
            // self-tagged publish: (h bits | epoch n+1) — single 8B atomic store
            const unsigned long long val =
                (unsigned long long)__builtin_bit_cast(unsigned int, h_reg)
                | ((unsigned long long)(unsigned int)(n + 1) << 32);
            __hip_atomic_store((par_w ? hWr1 : hWr0) + cb * CBC + jloc, val,
                               __ATOMIC_RELAXED, __HIP_MEMORY_SCOPE_AGENT);
            // history (read by out_kernel after kernel end) — off critical path
            __builtin_nontemporal_store(m ? h_reg : 0.f,
                hist + (((size_t)dir * BB + smp) * SS + ts) * HH + cb * CBC + jloc);
        }
        // no trailing barrier: stage double-buffer + B1 ordering make it safe
    }
}

// ---------------- K4: gate dot + sigmoid + per-row exact top-k ranks ----------------
// Grid (16 rows x 4 quads): each block recomputes its row's probs (cheap),
// then ranks 256 positions — 4x parallelism on the O(S^2) rank phase.
__global__ void out_kernel(const float* __restrict__ hist, const float* __restrict__ zw,
                           const float* __restrict__ zb, const int* __restrict__ lengths,
                           float* __restrict__ zout)
{
    const int b    = blockIdx.x;
    const int quad = blockIdx.y;
    const int t    = threadIdx.x;
    __shared__ float probs[SS];
    __shared__ float zwsh[2 * HH];
    __shared__ int lsh;
    zwsh[t] = zw[t];
    zwsh[HH + t] = zw[HH + t];
    if (t == 0) lsh = lengths[b];
    __syncthreads();
    const int len = lsh;
    const float zbv = zb[0];

    for (int s = t; s < SS; s += 256) {
        const float4* hf  = (const float4*)(hist + ((size_t)b * SS + s) * HH);
        const float4* hb2 = (const float4*)(hist + (((size_t)BB + b) * SS + s) * HH);
        const float4* z0 = (const float4*)zwsh;
        const float4* z1 = (const float4*)(zwsh + HH);
        float acc = 0.f;
#pragma unroll 8
        for (int q = 0; q < HH / 4; q++) {
            const float4 h = hf[q], zv = z0[q];
            acc = fmaf(h.x, zv.x, acc); acc = fmaf(h.y, zv.y, acc);
            acc = fmaf(h.z, zv.z, acc); acc = fmaf(h.w, zv.w, acc);
        }
#pragma unroll 8
        for (int q = 0; q < HH / 4; q++) {
            const float4 h = hb2[q], zv = z1[q];
            acc = fmaf(h.x, zv.x, acc); acc = fmaf(h.y, zv.y, acc);
            acc = fmaf(h.z, zv.z, acc); acc = fmaf(h.w, zv.w, acc);
        }
        const float d = acc + zbv;
        probs[s] = (s < len) ? 1.f / (1.f + expf(-d)) : 0.f;
    }
    __syncthreads();

    const int kb = (int)rintf(0.1f * (float)len);  // jnp.round = half-even
    const int s = quad * 256 + t;                  // one position per thread
    const float p = probs[s];
    int rank = 0;
    for (int j = 0; j < SS; j++) {
        const float pj = probs[j];
        rank += (pj > p) ? 1 : 0;
        rank += ((pj == p) && (j < s)) ? 1 : 0;
    }
    zout[b * SS + s] = (s < len && rank < kb) ? 1.f : 0.f;
}

// ---------------- launch ----------------
extern "C" void kernel_launch(void* const* d_in, const int* in_sizes, int n_in,
                              void* d_out, int out_size, void* d_ws, size_t ws_size,
                              hipStream_t stream)
{
    (void)in_sizes; (void)n_in; (void)out_size; (void)ws_size;
    const int*   x    = (const int*)d_in[0];
    const void*  mask = d_in[1];
    const float* emb  = (const float*)d_in[2];
    const float* wihf = (const float*)d_in[3];
    const float* whhf = (const float*)d_in[4];
    const float* bf   = (const float*)d_in[5];
    const float* wihb = (const float*)d_in[6];
    const float* whhb = (const float*)d_in[7];
    const float* bb   = (const float*)d_in[8];
    const float* zw   = (const float*)d_in[9];
    const float* zb   = (const float*)d_in[10];
    float* zout = (float*)d_out;

    char* ws = (char*)d_ws;
    unsigned long long* hbuf = (unsigned long long*)(ws + HBUF_OFF);
    int*   lengths           = (int*)(ws + LEN_OFF);
    float* hist              = (float*)(ws + HIST_OFF);
    float* xpF               = (float*)(ws + XPF_OFF);
    float* xpB               = (float*)(ws + XPB_OFF);

    // zero BOTH parities of the tagged h buffer (epoch 0, h = 0). The 0xAA
    // poison would satisfy the epoch>=n poll with garbage — correctness-critical.
    hipMemsetAsync(ws, 0, HBUF_BYTES, stream);

    len_kernel<<<BB, 256, 0, stream>>>(mask, lengths);
    xp_gemm<<<dim3((BB * SS) / GB_BM, (2 * G4) / GB_BN), 256, 0, stream>>>(
        x, emb, wihf, bf, wihb, bb, xpF, xpB);
    lstm_kernel<<<NCB * NCLUST, LTHR, 0, stream>>>(xpF, xpB, whhf, whhb, lengths,
                                                   hbuf, hist);
    out_kernel<<<dim3(BB, 4), 256, 0, stream>>>(hist, zw, zb, lengths, zout);
}